// Round 1
// baseline (427.350 us; speedup 1.0000x reference)
//
#include <hip/hip_runtime.h>
#include <hip/hip_bf16.h>
#include <cstdint>

#define BB 4
#define SS 4096
#define DD 1024
#define KK 32
#define HH 4
#define AA 2
#define TT 65536
#define NBB 16
#define DM 64
#define TV 32
#define MTOK (BB*SS)   // 16384

// ---------------- Kernel A: projections q[M,32], wk[M,32], v[M,64], gdot[M] ----
// out cols: [0,32)=q via Wq, [32,64)=wk via Ww, [64,128)=v via Wv, 128=g via Wg
__global__ __launch_bounds__(512) void proj_kernel(
    const float* __restrict__ u, const float* __restrict__ Wq,
    const float* __restrict__ Ww, const float* __restrict__ Wv,
    const float* __restrict__ Wg,
    float* __restrict__ q_o, float* __restrict__ wk_o,
    float* __restrict__ v_o, float* __restrict__ g_o)
{
    __shared__ float u_t[64][68];    // stride 68: float4-bank spread
    __shared__ float w_t[129][68];
    const int t  = threadIdx.x;
    const int m0 = blockIdx.x * 64;
    const int ty = t >> 5;           // 0..15 -> rows ty*4+i
    const int tx = t & 31;           // cols tx + 32*j

    float acc[4][5];
#pragma unroll
    for (int i = 0; i < 4; i++)
#pragma unroll
        for (int j = 0; j < 5; j++) acc[i][j] = 0.f;

    for (int k0 = 0; k0 < DD; k0 += 64) {
        __syncthreads();
        // u tile: 64x64 f32 = 1024 float4, 2 per thread
#pragma unroll
        for (int i = 0; i < 2; i++) {
            int e = t + i * 512;
            int r = e >> 4, cv = e & 15;
            float4 val = *(const float4*)(u + (size_t)(m0 + r) * DD + k0 + cv * 4);
            *(float4*)&u_t[r][cv * 4] = val;
        }
        // W tile: 129x64 f32 = 2064 float4
#pragma unroll
        for (int i = 0; i < 5; i++) {
            int e = t + i * 512;
            if (e < 2064) {
                int c = e >> 4, cv = e & 15;
                const float* wrow = (c < 32)  ? (Wq + (size_t)c * DD)
                                  : (c < 64)  ? (Ww + (size_t)(c - 32) * DD)
                                  : (c < 128) ? (Wv + (size_t)(c - 64) * DD)
                                              : Wg;
                float4 val = *(const float4*)(wrow + k0 + cv * 4);
                *(float4*)&w_t[c][cv * 4] = val;
            }
        }
        __syncthreads();
#pragma unroll
        for (int k4 = 0; k4 < 16; k4++) {
            float4 a4[4], b4[5];
#pragma unroll
            for (int i = 0; i < 4; i++) a4[i] = *(const float4*)&u_t[ty * 4 + i][k4 * 4];
#pragma unroll
            for (int j = 0; j < 4; j++) b4[j] = *(const float4*)&w_t[tx + j * 32][k4 * 4];
            b4[4] = *(const float4*)&w_t[128][k4 * 4];   // g col: broadcast, only tx==0 stores
#pragma unroll
            for (int i = 0; i < 4; i++)
#pragma unroll
                for (int j = 0; j < 5; j++) {
                    acc[i][j] = fmaf(a4[i].x, b4[j].x, acc[i][j]);
                    acc[i][j] = fmaf(a4[i].y, b4[j].y, acc[i][j]);
                    acc[i][j] = fmaf(a4[i].z, b4[j].z, acc[i][j]);
                    acc[i][j] = fmaf(a4[i].w, b4[j].w, acc[i][j]);
                }
        }
    }
#pragma unroll
    for (int i = 0; i < 4; i++) {
        int m = m0 + ty * 4 + i;
#pragma unroll
        for (int j = 0; j < 5; j++) {
            int c = tx + j * 32;
            if (c < 32)        q_o[(size_t)m * KK + c]        = acc[i][j];
            else if (c < 64)   wk_o[(size_t)m * KK + (c - 32)] = acc[i][j];
            else if (c < 128)  v_o[(size_t)m * DM + (c - 64)]  = acc[i][j];
            else if (tx == 0)  g_o[m] = acc[i][4];
        }
    }
}

// ---------------- Kernel B: routing + gather + read + write-prep ----------------
// 1 wave per token, 4 tokens per 256-thread block.
__global__ __launch_bounds__(256) void route_kernel(
    const float* __restrict__ R, const float* __restrict__ P,
    const float* __restrict__ mem_keys, const float* __restrict__ mem_vals,
    const float* __restrict__ mem_tags, const float* __restrict__ bg,
    const float* __restrict__ q_i, const float* __restrict__ wk_i,
    const float* __restrict__ g_i,
    float* __restrict__ read_o, float* __restrict__ wt_o,
    int* __restrict__ idx_o, int* __restrict__ slot_o, float* __restrict__ w_o)
{
    __shared__ float R_s[HH * KK * NBB];     // 2048 f32, layout [h][k][n]
    __shared__ float P_s[TV][KK + 1];        // padded
    __shared__ float q_s[4][KK], wk_s[4][KK], qt_s[4][TV], wt_s[4][TV];
    __shared__ float kg_s[4][8][KK], tg_s[4][8][TV], vg_s[4][8][DM];
    __shared__ float sc_s[4][8], mt_s[4][8];
    __shared__ int   idx_s[4][HH];

    const int t    = threadIdx.x;
    const int wid  = t >> 6;
    const int lane = t & 63;
    const int tok  = blockIdx.x * 4 + wid;

    for (int e = t; e < HH * KK * NBB; e += 256) R_s[e] = R[e];
    for (int e = t; e < TV * KK; e += 256) P_s[e >> 5][e & 31] = P[e];

    if (lane < 32) q_s[wid][lane] = q_i[(size_t)tok * KK + lane];
    else           wk_s[wid][lane - 32] = wk_i[(size_t)tok * KK + (lane - 32)];
    __syncthreads();

    // ---- bits -> bucket idx (lane = h*16 + n) ----
    {
        int h = lane >> 4, n = lane & 15;
        float s = 0.f;
#pragma unroll
        for (int k = 0; k < KK; k++) s = fmaf(q_s[wid][k], R_s[h * (KK * NBB) + k * NBB + n], s);
        unsigned long long m = __ballot(s > 0.f);
        if (n == 0) {
            int idx = (int)((m >> (h * 16)) & 0xFFFFull);
            idx_s[wid][h] = idx;
            idx_o[(size_t)tok * HH + h] = idx;
        }
    }
    // ---- qt (lanes 0..31), wt (lanes 32..63) ----
    if (lane < 32) {
        float s = 0.f;
#pragma unroll
        for (int k = 0; k < KK; k++) s = fmaf(q_s[wid][k], P_s[lane][k], s);
        qt_s[wid][lane] = tanhf(s);
    } else {
        int t2 = lane - 32;
        float s = 0.f;
#pragma unroll
        for (int k = 0; k < KK; k++) s = fmaf(wk_s[wid][k], P_s[t2][k], s);
        float wtv = tanhf(s);
        wt_s[wid][t2] = wtv;
        wt_o[(size_t)tok * TV + t2] = wtv;
    }
    __syncthreads();

    // ---- gather 8 slots: pair p = lane>>3 (h=p>>1, a=p&1), j = lane&7 ----
    {
        int p = lane >> 3, j = lane & 7;
        int h = p >> 1, a = p & 1;
        size_t sb = (size_t)idx_s[wid][h] * AA + a;
        *(float4*)&kg_s[wid][p][j * 4] = *(const float4*)(mem_keys + sb * KK + j * 4);
        *(float4*)&tg_s[wid][p][j * 4] = *(const float4*)(mem_tags + sb * TV + j * 4);
        *(float4*)&vg_s[wid][p][j * 8]     = *(const float4*)(mem_vals + sb * DM + j * 8);
        *(float4*)&vg_s[wid][p][j * 8 + 4] = *(const float4*)(mem_vals + sb * DM + j * 8 + 4);
    }
    __syncthreads();

    // ---- scores (lanes 0..7) and match (lanes 8..15) ----
    if (lane < 8) {
        int p = lane;
        float s1 = 0.f, s2 = 0.f;
#pragma unroll
        for (int k = 0; k < KK; k++) s1 = fmaf(q_s[wid][k], kg_s[wid][p][k], s1);
#pragma unroll
        for (int k = 0; k < TV; k++) s2 = fmaf(qt_s[wid][k], tg_s[wid][p][k], s2);
        sc_s[wid][p] = s1 * 0.17677669529663688f + s2 * (1.0f / 32.0f);
    } else if (lane < 16) {
        int p = lane - 8;
        float s2 = 0.f;
#pragma unroll
        for (int k = 0; k < TV; k++) s2 = fmaf(wt_s[wid][k], tg_s[wid][p][k], s2);
        mt_s[wid][p] = s2 * (1.0f / 32.0f);
    }
    __syncthreads();

    // ---- softmax over 8 (redundant per lane) + read (lane = d) ----
    {
        float sc[8];
#pragma unroll
        for (int p = 0; p < 8; p++) sc[p] = sc_s[wid][p];
        float mx = sc[0];
#pragma unroll
        for (int p = 1; p < 8; p++) mx = fmaxf(mx, sc[p]);
        float e[8], den = 0.f;
#pragma unroll
        for (int p = 0; p < 8; p++) { e[p] = expf(sc[p] - mx); den += e[p]; }
        float inv = 1.f / den;
        float r = 0.f;
#pragma unroll
        for (int p = 0; p < 8; p++) r = fmaf(e[p] * inv, vg_s[wid][p][lane], r);
        read_o[(size_t)tok * DM + lane] = r;
    }
    // ---- write gate (lanes 0..3 = h) ----
    if (lane < HH) {
        int h = lane;
        float m0v = mt_s[wid][h * 2], m1v = mt_s[wid][h * 2 + 1];
        int sl = (m1v > m0v) ? 1 : 0;
        float mm = fmaxf(m0v, m1v);
        float nov = 1.f / (1.f + expf(mm));          // sigmoid(-mm), BETA=1, THR=0
        float gd = g_i[tok] + bg[0];
        float gg = 1.f / (1.f + expf(-gd));
        float wv = (gg > 0.5f) ? (0.1f * gg * nov) : 0.f;   // ETA * g * nov if g>WRITE_THR
        slot_o[(size_t)tok * HH + h] = sl;
        w_o[(size_t)tok * HH + h] = wv;
    }
}

// ---------------- Kernel C: y = read @ Wout^T ----------------
__global__ __launch_bounds__(256) void ygemm_kernel(
    const float* __restrict__ read_i, const float* __restrict__ Wout,
    float* __restrict__ y_o)
{
    __shared__ float rd_t[64][68];
    __shared__ float wo_t[64][68];
    const int t  = threadIdx.x;
    const int m0 = blockIdx.x * 64;
    const int n0 = blockIdx.y * 64;
#pragma unroll
    for (int i = 0; i < 4; i++) {
        int e = t + i * 256;
        int r = e >> 4, cv = e & 15;
        *(float4*)&rd_t[r][cv * 4] = *(const float4*)(read_i + (size_t)(m0 + r) * DM + cv * 4);
        *(float4*)&wo_t[r][cv * 4] = *(const float4*)(Wout  + (size_t)(n0 + r) * DM + cv * 4);
    }
    __syncthreads();
    const int ty = t >> 4;   // rows ty*4+i
    const int tx = t & 15;   // cols tx + 16*j  (strided for bank spread)
    float acc[4][4];
#pragma unroll
    for (int i = 0; i < 4; i++)
#pragma unroll
        for (int j = 0; j < 4; j++) acc[i][j] = 0.f;
#pragma unroll
    for (int k4 = 0; k4 < 16; k4++) {
        float4 a4[4], b4[4];
#pragma unroll
        for (int i = 0; i < 4; i++) a4[i] = *(const float4*)&rd_t[ty * 4 + i][k4 * 4];
#pragma unroll
        for (int j = 0; j < 4; j++) b4[j] = *(const float4*)&wo_t[tx + j * 16][k4 * 4];
#pragma unroll
        for (int i = 0; i < 4; i++)
#pragma unroll
            for (int j = 0; j < 4; j++) {
                acc[i][j] = fmaf(a4[i].x, b4[j].x, acc[i][j]);
                acc[i][j] = fmaf(a4[i].y, b4[j].y, acc[i][j]);
                acc[i][j] = fmaf(a4[i].z, b4[j].z, acc[i][j]);
                acc[i][j] = fmaf(a4[i].w, b4[j].w, acc[i][j]);
            }
    }
#pragma unroll
    for (int i = 0; i < 4; i++) {
        size_t row = (size_t)(m0 + ty * 4 + i) * DD + n0;
#pragma unroll
        for (int j = 0; j < 4; j++) y_o[row + tx + j * 16] = acc[i][j];
    }
}

// ---------------- Kernel D: scatter-add deltas into table copies ----------------
__global__ __launch_bounds__(256) void scatter_kernel(
    const float* __restrict__ mem_keys, const float* __restrict__ mem_vals,
    const float* __restrict__ mem_tags,
    const float* __restrict__ wk_i, const float* __restrict__ v_i,
    const float* __restrict__ wt_i,
    const int* __restrict__ idx_i, const int* __restrict__ slot_i,
    const float* __restrict__ w_i,
    float* __restrict__ keys_o, float* __restrict__ vals_o, float* __restrict__ tags_o)
{
    int op   = blockIdx.x * 8 + (threadIdx.x >> 5);   // (tok*H + h)
    int lane = threadIdx.x & 31;
    float w = w_i[op];
    if (w == 0.f) return;                             // g-gate closed: exact zero
    int tok = op >> 2;
    size_t flat = (size_t)idx_i[op] * AA + slot_i[op];
    {
        float d = w * (wk_i[(size_t)tok * KK + lane] - mem_keys[flat * KK + lane]);
        atomicAdd(keys_o + flat * KK + lane, d);
    }
    {
        float d = w * (wt_i[(size_t)tok * TV + lane] - mem_tags[flat * TV + lane]);
        atomicAdd(tags_o + flat * TV + lane, d);
    }
#pragma unroll
    for (int h2 = 0; h2 < 2; h2++) {
        int d2 = lane + h2 * 32;
        float d = w * (v_i[(size_t)tok * DM + d2] - mem_vals[flat * DM + d2]);
        atomicAdd(vals_o + flat * DM + d2, d);
    }
}

extern "C" void kernel_launch(void* const* d_in, const int* in_sizes, int n_in,
                              void* d_out, int out_size, void* d_ws, size_t ws_size,
                              hipStream_t stream)
{
    (void)in_sizes; (void)n_in; (void)out_size; (void)ws_size;
    const float* u    = (const float*)d_in[0];
    const float* Wq   = (const float*)d_in[1];
    const float* Ww   = (const float*)d_in[2];
    const float* Wv   = (const float*)d_in[3];
    const float* Wout = (const float*)d_in[4];
    const float* Wg   = (const float*)d_in[5];
    const float* bg   = (const float*)d_in[6];
    const float* R    = (const float*)d_in[7];
    const float* P    = (const float*)d_in[8];
    const float* mem_keys = (const float*)d_in[9];
    const float* mem_vals = (const float*)d_in[10];
    const float* mem_tags = (const float*)d_in[11];

    float* ws    = (float*)d_ws;
    float* q_w   = ws;
    float* wk_w  = q_w  + (size_t)MTOK * KK;
    float* v_w   = wk_w + (size_t)MTOK * KK;
    float* g_w   = v_w  + (size_t)MTOK * DM;
    float* read_w= g_w  + MTOK;
    float* wt_w  = read_w + (size_t)MTOK * DM;
    float* w_w   = wt_w + (size_t)MTOK * TV;
    int*   idx_w = (int*)(w_w + (size_t)MTOK * HH);
    int*   slot_w= idx_w + (size_t)MTOK * HH;

    float* y_o    = (float*)d_out;
    float* keys_o = y_o    + (size_t)MTOK * DD;
    float* vals_o = keys_o + (size_t)TT * AA * KK;
    float* tags_o = vals_o + (size_t)TT * AA * DM;

    // table copies into output (scatter adds deltas on top)
    hipMemcpyAsync(keys_o, mem_keys, (size_t)TT * AA * KK * sizeof(float), hipMemcpyDeviceToDevice, stream);
    hipMemcpyAsync(vals_o, mem_vals, (size_t)TT * AA * DM * sizeof(float), hipMemcpyDeviceToDevice, stream);
    hipMemcpyAsync(tags_o, mem_tags, (size_t)TT * AA * TV * sizeof(float), hipMemcpyDeviceToDevice, stream);

    proj_kernel<<<MTOK / 64, 512, 0, stream>>>(u, Wq, Ww, Wv, Wg, q_w, wk_w, v_w, g_w);
    route_kernel<<<MTOK / 4, 256, 0, stream>>>(R, P, mem_keys, mem_vals, mem_tags, bg,
                                               q_w, wk_w, g_w, read_w, wt_w, idx_w, slot_w, w_w);
    ygemm_kernel<<<dim3(MTOK / 64, DD / 64), 256, 0, stream>>>(read_w, Wout, y_o);
    scatter_kernel<<<MTOK * HH / 8, 256, 0, stream>>>(mem_keys, mem_vals, mem_tags,
        wk_w, v_w, wt_w, idx_w, slot_w, w_w, keys_o, vals_o, tags_o);
}

// Round 3
// 370.860 us; speedup vs baseline: 1.1523x; 1.1523x over previous
//
#include <hip/hip_runtime.h>
#include <hip/hip_bf16.h>
#include <cstdint>

#define BB 4
#define SS 4096
#define DD 1024
#define KK 32
#define HH 4
#define AA 2
#define TT 65536
#define NBB 16
#define DM 64
#define TV 32
#define MTOK (BB*SS)   // 16384
#define PKS 4          // K slices for proj
#define PKL (DD/PKS)   // 256

// wave-level LDS fence: all of THIS wave's outstanding LDS ops complete.
#define WAVE_FENCE() asm volatile("s_waitcnt lgkmcnt(0)" ::: "memory")

// ---------------- Kernel A: projections, K-split x4, K-tile 32 ----------------
// Per block: 128-row M-tile, 128 output cols (q32|wk32|v64), K-slice 256.
// g fused into staging. Partials per-slice; consumers reduce. LDS = 36,864 B.
__global__ __launch_bounds__(256, 2) void proj_kernel(
    const float* __restrict__ u, const float* __restrict__ Wq,
    const float* __restrict__ Ww, const float* __restrict__ Wv,
    const float* __restrict__ Wg,
    float* __restrict__ qs, float* __restrict__ wks,
    float* __restrict__ vs, float* __restrict__ gs)
{
    __shared__ float u_t[128][36];
    __shared__ float w_t[128][36];
    const int t  = threadIdx.x;
    const int mb = blockIdx.x & 127;
    const int ks = blockIdx.x >> 7;
    const int m0 = mb * 128;
    const int kb = ks * PKL;
    const int r0 = t >> 3;     // staging row 0..31 (+32p)
    const int c8 = t & 7;      // staging float4-column
    const int ty = t >> 4;     // compute: rows ty + 16*i
    const int tx = t & 15;     // compute: cols tx + 16*j

    float acc[8][8];
#pragma unroll
    for (int i = 0; i < 8; i++)
#pragma unroll
        for (int j = 0; j < 8; j++) acc[i][j] = 0.f;
    float gp[4] = {0.f, 0.f, 0.f, 0.f};

    for (int k0 = 0; k0 < PKL; k0 += 32) {
        const float4 wg4 = *(const float4*)(Wg + kb + k0 + c8 * 4);
        __syncthreads();
        // stage u: 128 rows x 8 float4 (4 per thread); fuse g-partial
#pragma unroll
        for (int p = 0; p < 4; p++) {
            int r = r0 + 32 * p;
            float4 uv = *(const float4*)(u + (size_t)(m0 + r) * DD + kb + k0 + c8 * 4);
            *(float4*)&u_t[r][c8 * 4] = uv;
            gp[p] = fmaf(uv.x, wg4.x, fmaf(uv.y, wg4.y, fmaf(uv.z, wg4.z, fmaf(uv.w, wg4.w, gp[p]))));
        }
        // stage W: 128 rows x 8 float4 (4 per thread)
#pragma unroll
        for (int p = 0; p < 4; p++) {
            int c = r0 + 32 * p;
            const float* wrow = (c < 32)  ? (Wq + (size_t)c * DD)
                              : (c < 64)  ? (Ww + (size_t)(c - 32) * DD)
                                          : (Wv + (size_t)(c - 64) * DD);
            *(float4*)&w_t[c][c8 * 4] = *(const float4*)(wrow + kb + k0 + c8 * 4);
        }
        __syncthreads();
#pragma unroll
        for (int k4 = 0; k4 < 8; k4++) {
            float4 a4[8], b4[8];
#pragma unroll
            for (int i = 0; i < 8; i++) a4[i] = *(const float4*)&u_t[ty + 16 * i][k4 * 4];
#pragma unroll
            for (int j = 0; j < 8; j++) b4[j] = *(const float4*)&w_t[tx + 16 * j][k4 * 4];
#pragma unroll
            for (int i = 0; i < 8; i++)
#pragma unroll
                for (int j = 0; j < 8; j++) {
                    acc[i][j] = fmaf(a4[i].x, b4[j].x, acc[i][j]);
                    acc[i][j] = fmaf(a4[i].y, b4[j].y, acc[i][j]);
                    acc[i][j] = fmaf(a4[i].z, b4[j].z, acc[i][j]);
                    acc[i][j] = fmaf(a4[i].w, b4[j].w, acc[i][j]);
                }
        }
    }
    // g reduce across the 8 c8 lanes (consecutive within wave)
#pragma unroll
    for (int p = 0; p < 4; p++) {
        gp[p] += __shfl_xor(gp[p], 1);
        gp[p] += __shfl_xor(gp[p], 2);
        gp[p] += __shfl_xor(gp[p], 4);
    }
    if (c8 == 0) {
#pragma unroll
        for (int p = 0; p < 4; p++) gs[(size_t)ks * MTOK + m0 + r0 + 32 * p] = gp[p];
    }
#pragma unroll
    for (int i = 0; i < 8; i++) {
        int row = m0 + ty + 16 * i;
#pragma unroll
        for (int j = 0; j < 8; j++) {
            if (j < 2)      qs[(size_t)ks * MTOK * KK + (size_t)row * KK + tx + 16 * j]        = acc[i][j];
            else if (j < 4) wks[(size_t)ks * MTOK * KK + (size_t)row * KK + tx + 16 * (j - 2)] = acc[i][j];
            else            vs[(size_t)ks * MTOK * DM + (size_t)row * DM + tx + 16 * (j - 4)]  = acc[i][j];
        }
    }
}

// ---------------- Kernel B: routing + gather + read + write-prep ----------------
// 16 tokens per 256-thread block; each wave loops over 4 tokens.
// Phase buffers are wave-private; wave fences (not block barriers) between phases.
__global__ __launch_bounds__(256) void route_kernel(
    const float* __restrict__ R, const float* __restrict__ P,
    const float* __restrict__ mem_keys, const float* __restrict__ mem_vals,
    const float* __restrict__ mem_tags, const float* __restrict__ bg,
    const float* __restrict__ qs, const float* __restrict__ wks,
    const float* __restrict__ gsl,
    float* __restrict__ read_o, float* __restrict__ wt_o,
    int* __restrict__ idx_o, int* __restrict__ slot_o, float* __restrict__ w_o)
{
    __shared__ float R_s[4 * 528];           // h*528 + k*16 + n
    __shared__ float P_s[TV][KK + 1];
    __shared__ float q_s[4][KK], wk_s[4][KK], qt_s[4][TV], wt_s[4][TV];
    __shared__ float kg_s[4][8][KK], tg_s[4][8][TV], vg_s[4][8][DM];
    __shared__ float sc_s[4][8], mt_s[4][8];
    __shared__ int   idx_s[4][HH];

    const int t    = threadIdx.x;
    const int wid  = t >> 6;
    const int lane = t & 63;

    for (int e = t; e < 2048; e += 256) R_s[(e >> 9) * 528 + (e & 511)] = R[e];
    for (int e = t; e < TV * KK; e += 256) P_s[e >> 5][e & 31] = P[e];
    const float bgv = bg[0];
    __syncthreads();

    for (int ti = 0; ti < 4; ti++) {
        const int tok = blockIdx.x * 16 + wid * 4 + ti;
        // phase 1: load q/wk (reduce K-slices)
        if (lane < 32) {
            float s = 0.f;
#pragma unroll
            for (int sl = 0; sl < PKS; sl++) s += qs[(size_t)sl * MTOK * KK + (size_t)tok * KK + lane];
            q_s[wid][lane] = s;
        } else {
            int l2 = lane - 32;
            float s = 0.f;
#pragma unroll
            for (int sl = 0; sl < PKS; sl++) s += wks[(size_t)sl * MTOK * KK + (size_t)tok * KK + l2];
            wk_s[wid][l2] = s;
        }
        WAVE_FENCE();
        // phase 2: bits -> bucket idx (lane = h*16 + n)
        {
            int h = lane >> 4, n = lane & 15;
            float s = 0.f;
#pragma unroll
            for (int k = 0; k < KK; k++) s = fmaf(q_s[wid][k], R_s[h * 528 + k * 16 + n], s);
            unsigned long long m = __ballot(s > 0.f);
            if (n == 0) {
                int idx = (int)((m >> (h * 16)) & 0xFFFFull);
                idx_s[wid][h] = idx;
                idx_o[(size_t)tok * HH + h] = idx;
            }
        }
        // phase 3: qt (lanes 0..31), wt (lanes 32..63)
        if (lane < 32) {
            float s = 0.f;
#pragma unroll
            for (int k = 0; k < KK; k++) s = fmaf(q_s[wid][k], P_s[lane][k], s);
            qt_s[wid][lane] = tanhf(s);
        } else {
            int t2 = lane - 32;
            float s = 0.f;
#pragma unroll
            for (int k = 0; k < KK; k++) s = fmaf(wk_s[wid][k], P_s[t2][k], s);
            float wtv = tanhf(s);
            wt_s[wid][t2] = wtv;
            wt_o[(size_t)tok * TV + t2] = wtv;
        }
        WAVE_FENCE();
        // phase 4: gather 8 slots
        {
            int p = lane >> 3, j = lane & 7;
            int h = p >> 1, a = p & 1;
            size_t sb = (size_t)idx_s[wid][h] * AA + a;
            *(float4*)&kg_s[wid][p][j * 4] = *(const float4*)(mem_keys + sb * KK + j * 4);
            *(float4*)&tg_s[wid][p][j * 4] = *(const float4*)(mem_tags + sb * TV + j * 4);
            *(float4*)&vg_s[wid][p][j * 8]     = *(const float4*)(mem_vals + sb * DM + j * 8);
            *(float4*)&vg_s[wid][p][j * 8 + 4] = *(const float4*)(mem_vals + sb * DM + j * 8 + 4);
        }
        WAVE_FENCE();
        // phase 5: scores (lanes 0..7) and match (lanes 8..15)
        if (lane < 8) {
            int p = lane;
            float s1 = 0.f, s2 = 0.f;
#pragma unroll
            for (int k = 0; k < KK; k++) s1 = fmaf(q_s[wid][k], kg_s[wid][p][k], s1);
#pragma unroll
            for (int k = 0; k < TV; k++) s2 = fmaf(qt_s[wid][k], tg_s[wid][p][k], s2);
            sc_s[wid][p] = s1 * 0.17677669529663688f + s2 * (1.0f / 32.0f);
        } else if (lane < 16) {
            int p = lane - 8;
            float s2 = 0.f;
#pragma unroll
            for (int k = 0; k < TV; k++) s2 = fmaf(wt_s[wid][k], tg_s[wid][p][k], s2);
            mt_s[wid][p] = s2 * (1.0f / 32.0f);
        }
        WAVE_FENCE();
        // phase 6: softmax over 8 + read (lane = d)
        {
            float sc[8];
#pragma unroll
            for (int p = 0; p < 8; p++) sc[p] = sc_s[wid][p];
            float mx = sc[0];
#pragma unroll
            for (int p = 1; p < 8; p++) mx = fmaxf(mx, sc[p]);
            float e[8], den = 0.f;
#pragma unroll
            for (int p = 0; p < 8; p++) { e[p] = expf(sc[p] - mx); den += e[p]; }
            float inv = 1.f / den;
            float r = 0.f;
#pragma unroll
            for (int p = 0; p < 8; p++) r = fmaf(e[p] * inv, vg_s[wid][p][lane], r);
            read_o[(size_t)tok * DM + lane] = r;
        }
        // phase 7: write gate (lanes 0..3 = h)
        if (lane < HH) {
            int h = lane;
            float m0v = mt_s[wid][h * 2], m1v = mt_s[wid][h * 2 + 1];
            int sl = (m1v > m0v) ? 1 : 0;
            float mm = fmaxf(m0v, m1v);
            float nov = 1.f / (1.f + expf(mm));
            float gd = bgv;
#pragma unroll
            for (int s2 = 0; s2 < PKS; s2++) gd += gsl[(size_t)s2 * MTOK + tok];
            float gg = 1.f / (1.f + expf(-gd));
            float wv = (gg > 0.5f) ? (0.1f * gg * nov) : 0.f;
            slot_o[(size_t)tok * HH + h] = sl;
            w_o[(size_t)tok * HH + h] = wv;
        }
        WAVE_FENCE();   // WAR: next iter overwrites q_s/wk_s etc.
    }
}

// ---------------- Kernel C: y = read @ Wout^T ----------------
__global__ __launch_bounds__(256) void ygemm_kernel(
    const float* __restrict__ read_i, const float* __restrict__ Wout,
    float* __restrict__ y_o)
{
    __shared__ float rd_t[64][68];
    __shared__ float wo_t[64][68];
    const int t  = threadIdx.x;
    const int m0 = blockIdx.x * 64;
    const int n0 = blockIdx.y * 64;
#pragma unroll
    for (int i = 0; i < 4; i++) {
        int e = t + i * 256;
        int r = e >> 4, cv = e & 15;
        *(float4*)&rd_t[r][cv * 4] = *(const float4*)(read_i + (size_t)(m0 + r) * DM + cv * 4);
        *(float4*)&wo_t[r][cv * 4] = *(const float4*)(Wout  + (size_t)(n0 + r) * DM + cv * 4);
    }
    __syncthreads();
    const int ty = t >> 4;
    const int tx = t & 15;
    float acc[4][4];
#pragma unroll
    for (int i = 0; i < 4; i++)
#pragma unroll
        for (int j = 0; j < 4; j++) acc[i][j] = 0.f;
#pragma unroll
    for (int k4 = 0; k4 < 16; k4++) {
        float4 a4[4], b4[4];
#pragma unroll
        for (int i = 0; i < 4; i++) a4[i] = *(const float4*)&rd_t[ty * 4 + i][k4 * 4];
#pragma unroll
        for (int j = 0; j < 4; j++) b4[j] = *(const float4*)&wo_t[tx + j * 16][k4 * 4];
#pragma unroll
        for (int i = 0; i < 4; i++)
#pragma unroll
            for (int j = 0; j < 4; j++) {
                acc[i][j] = fmaf(a4[i].x, b4[j].x, acc[i][j]);
                acc[i][j] = fmaf(a4[i].y, b4[j].y, acc[i][j]);
                acc[i][j] = fmaf(a4[i].z, b4[j].z, acc[i][j]);
                acc[i][j] = fmaf(a4[i].w, b4[j].w, acc[i][j]);
            }
    }
#pragma unroll
    for (int i = 0; i < 4; i++) {
        size_t row = (size_t)(m0 + ty * 4 + i) * DD + n0;
#pragma unroll
        for (int j = 0; j < 4; j++) y_o[row + tx + j * 16] = acc[i][j];
    }
}

// ---------------- Kernel D: scatter-add deltas into table copies ----------------
__global__ __launch_bounds__(256) void scatter_kernel(
    const float* __restrict__ mem_keys, const float* __restrict__ mem_vals,
    const float* __restrict__ mem_tags,
    const float* __restrict__ wks, const float* __restrict__ vsl,
    const float* __restrict__ wt_i,
    const int* __restrict__ idx_i, const int* __restrict__ slot_i,
    const float* __restrict__ w_i,
    float* __restrict__ keys_o, float* __restrict__ vals_o, float* __restrict__ tags_o)
{
    int op   = blockIdx.x * 8 + (threadIdx.x >> 5);
    int lane = threadIdx.x & 31;
    float w = w_i[op];
    if (w == 0.f) return;
    int tok = op >> 2;
    size_t flat = (size_t)idx_i[op] * AA + slot_i[op];
    {
        float wkv = 0.f;
#pragma unroll
        for (int sl = 0; sl < PKS; sl++) wkv += wks[(size_t)sl * MTOK * KK + (size_t)tok * KK + lane];
        float d = w * (wkv - mem_keys[flat * KK + lane]);
        atomicAdd(keys_o + flat * KK + lane, d);
    }
    {
        float d = w * (wt_i[(size_t)tok * TV + lane] - mem_tags[flat * TV + lane]);
        atomicAdd(tags_o + flat * TV + lane, d);
    }
#pragma unroll
    for (int h2 = 0; h2 < 2; h2++) {
        int d2 = lane + h2 * 32;
        float vv = 0.f;
#pragma unroll
        for (int sl = 0; sl < PKS; sl++) vv += vsl[(size_t)sl * MTOK * DM + (size_t)tok * DM + d2];
        float d = w * (vv - mem_vals[flat * DM + d2]);
        atomicAdd(vals_o + flat * DM + d2, d);
    }
}

extern "C" void kernel_launch(void* const* d_in, const int* in_sizes, int n_in,
                              void* d_out, int out_size, void* d_ws, size_t ws_size,
                              hipStream_t stream)
{
    (void)in_sizes; (void)n_in; (void)out_size; (void)ws_size;
    const float* u    = (const float*)d_in[0];
    const float* Wq   = (const float*)d_in[1];
    const float* Ww   = (const float*)d_in[2];
    const float* Wv   = (const float*)d_in[3];
    const float* Wout = (const float*)d_in[4];
    const float* Wg   = (const float*)d_in[5];
    const float* bg   = (const float*)d_in[6];
    const float* R    = (const float*)d_in[7];
    const float* P    = (const float*)d_in[8];
    const float* mem_keys = (const float*)d_in[9];
    const float* mem_vals = (const float*)d_in[10];
    const float* mem_tags = (const float*)d_in[11];

    float* y_o    = (float*)d_out;
    float* keys_o = y_o    + (size_t)MTOK * DD;
    float* vals_o = keys_o + (size_t)TT * AA * KK;
    float* tags_o = vals_o + (size_t)TT * AA * DM;

    // proj K-slice partials live in the (not-yet-written) y region of d_out:
    // 4*M*32 + 4*M*32 + 4*M*64 + 4*M = 8.45M floats < 16.78M available.
    // ygemm overwrites this region LAST.
    float* qs  = y_o;
    float* wks = qs  + (size_t)PKS * MTOK * KK;
    float* vsl = wks + (size_t)PKS * MTOK * KK;
    float* gsl = vsl + (size_t)PKS * MTOK * DM;

    float* ws     = (float*)d_ws;
    float* read_w = ws;
    float* wt_w   = read_w + (size_t)MTOK * DM;
    float* w_w    = wt_w   + (size_t)MTOK * TV;
    int*   idx_w  = (int*)(w_w + (size_t)MTOK * HH);
    int*   slot_w = idx_w + (size_t)MTOK * HH;

    hipMemcpyAsync(keys_o, mem_keys, (size_t)TT * AA * KK * sizeof(float), hipMemcpyDeviceToDevice, stream);
    hipMemcpyAsync(vals_o, mem_vals, (size_t)TT * AA * DM * sizeof(float), hipMemcpyDeviceToDevice, stream);
    hipMemcpyAsync(tags_o, mem_tags, (size_t)TT * AA * TV * sizeof(float), hipMemcpyDeviceToDevice, stream);

    proj_kernel<<<128 * PKS, 256, 0, stream>>>(u, Wq, Ww, Wv, Wg, qs, wks, vsl, gsl);
    route_kernel<<<MTOK / 16, 256, 0, stream>>>(R, P, mem_keys, mem_vals, mem_tags, bg,
                                                qs, wks, gsl, read_w, wt_w, idx_w, slot_w, w_w);
    scatter_kernel<<<MTOK * HH / 8, 256, 0, stream>>>(mem_keys, mem_vals, mem_tags,
        wks, vsl, wt_w, idx_w, slot_w, w_w, keys_o, vals_o, tags_o);
    ygemm_kernel<<<dim3(MTOK / 64, DD / 64), 256, 0, stream>>>(read_w, Wout, y_o);
}

// Round 4
// 369.916 us; speedup vs baseline: 1.1553x; 1.0025x over previous
//
#include <hip/hip_runtime.h>
#include <hip/hip_bf16.h>
#include <cstdint>

#define BB 4
#define SS 4096
#define DD 1024
#define KK 32
#define HH 4
#define AA 2
#define TT 65536
#define NBB 16
#define DM 64
#define TV 32
#define MTOK (BB*SS)   // 16384
#define PKS 4          // K slices for proj
#define PKL (DD/PKS)   // 256

// wave-level LDS fence: all of THIS wave's outstanding LDS ops complete.
#define WAVE_FENCE() asm volatile("s_waitcnt lgkmcnt(0)" ::: "memory")

// ---------------- Kernel 0: copy tables input -> output (one pass) ----------
// keys|vals|tags are contiguous in d_out after y. 16,777,216 floats total.
__global__ __launch_bounds__(256) void copy_kernel(
    const float* __restrict__ mem_keys, const float* __restrict__ mem_vals,
    const float* __restrict__ mem_tags, float* __restrict__ tab_o)
{
    const size_t NK = (size_t)TT * AA * KK;      // 4,194,304
    const size_t NV = (size_t)TT * AA * DM;      // 8,388,608
    const size_t NT = (size_t)TT * AA * TV;      // 4,194,304
    const size_t total4 = (NK + NV + NT) / 4;    // 4,194,304 float4
    size_t i = (size_t)blockIdx.x * 256 + threadIdx.x;
    const size_t stride = (size_t)gridDim.x * 256;
    for (; i < total4; i += stride) {
        size_t e = i * 4;
        float4 val;
        if (e < NK)           val = *(const float4*)(mem_keys + e);
        else if (e < NK + NV) val = *(const float4*)(mem_vals + (e - NK));
        else                  val = *(const float4*)(mem_tags + (e - NK - NV));
        *(float4*)(tab_o + e) = val;
    }
}

// ---------------- Kernel A: projections, K-split x4, K-tile 32 ----------------
__global__ __launch_bounds__(256, 2) void proj_kernel(
    const float* __restrict__ u, const float* __restrict__ Wq,
    const float* __restrict__ Ww, const float* __restrict__ Wv,
    const float* __restrict__ Wg,
    float* __restrict__ qs, float* __restrict__ wks,
    float* __restrict__ vs, float* __restrict__ gs)
{
    __shared__ float u_t[128][36];
    __shared__ float w_t[128][36];
    const int t  = threadIdx.x;
    const int mb = blockIdx.x & 127;
    const int ks = blockIdx.x >> 7;
    const int m0 = mb * 128;
    const int kb = ks * PKL;
    const int r0 = t >> 3;     // staging row 0..31 (+32p)
    const int c8 = t & 7;      // staging float4-column
    const int ty = t >> 4;     // compute: rows ty + 16*i
    const int tx = t & 15;     // compute: cols tx + 16*j

    float acc[8][8];
#pragma unroll
    for (int i = 0; i < 8; i++)
#pragma unroll
        for (int j = 0; j < 8; j++) acc[i][j] = 0.f;
    float gp[4] = {0.f, 0.f, 0.f, 0.f};

    for (int k0 = 0; k0 < PKL; k0 += 32) {
        const float4 wg4 = *(const float4*)(Wg + kb + k0 + c8 * 4);
        __syncthreads();
#pragma unroll
        for (int p = 0; p < 4; p++) {
            int r = r0 + 32 * p;
            float4 uv = *(const float4*)(u + (size_t)(m0 + r) * DD + kb + k0 + c8 * 4);
            *(float4*)&u_t[r][c8 * 4] = uv;
            gp[p] = fmaf(uv.x, wg4.x, fmaf(uv.y, wg4.y, fmaf(uv.z, wg4.z, fmaf(uv.w, wg4.w, gp[p]))));
        }
#pragma unroll
        for (int p = 0; p < 4; p++) {
            int c = r0 + 32 * p;
            const float* wrow = (c < 32)  ? (Wq + (size_t)c * DD)
                              : (c < 64)  ? (Ww + (size_t)(c - 32) * DD)
                                          : (Wv + (size_t)(c - 64) * DD);
            *(float4*)&w_t[c][c8 * 4] = *(const float4*)(wrow + kb + k0 + c8 * 4);
        }
        __syncthreads();
#pragma unroll
        for (int k4 = 0; k4 < 8; k4++) {
            float4 a4[8], b4[8];
#pragma unroll
            for (int i = 0; i < 8; i++) a4[i] = *(const float4*)&u_t[ty + 16 * i][k4 * 4];
#pragma unroll
            for (int j = 0; j < 8; j++) b4[j] = *(const float4*)&w_t[tx + 16 * j][k4 * 4];
#pragma unroll
            for (int i = 0; i < 8; i++)
#pragma unroll
                for (int j = 0; j < 8; j++) {
                    acc[i][j] = fmaf(a4[i].x, b4[j].x, acc[i][j]);
                    acc[i][j] = fmaf(a4[i].y, b4[j].y, acc[i][j]);
                    acc[i][j] = fmaf(a4[i].z, b4[j].z, acc[i][j]);
                    acc[i][j] = fmaf(a4[i].w, b4[j].w, acc[i][j]);
                }
        }
    }
#pragma unroll
    for (int p = 0; p < 4; p++) {
        gp[p] += __shfl_xor(gp[p], 1);
        gp[p] += __shfl_xor(gp[p], 2);
        gp[p] += __shfl_xor(gp[p], 4);
    }
    if (c8 == 0) {
#pragma unroll
        for (int p = 0; p < 4; p++) gs[(size_t)ks * MTOK + m0 + r0 + 32 * p] = gp[p];
    }
#pragma unroll
    for (int i = 0; i < 8; i++) {
        int row = m0 + ty + 16 * i;
#pragma unroll
        for (int j = 0; j < 8; j++) {
            if (j < 2)      qs[(size_t)ks * MTOK * KK + (size_t)row * KK + tx + 16 * j]        = acc[i][j];
            else if (j < 4) wks[(size_t)ks * MTOK * KK + (size_t)row * KK + tx + 16 * (j - 2)] = acc[i][j];
            else            vs[(size_t)ks * MTOK * DM + (size_t)row * DM + tx + 16 * (j - 4)]  = acc[i][j];
        }
    }
}

// ---------------- Kernel B: routing + gather + read + fused scatter ------------
// 16 tokens per 256-thread block; each wave loops over 4 tokens; wave fences.
__global__ __launch_bounds__(256) void route_kernel(
    const float* __restrict__ R, const float* __restrict__ P,
    const float* __restrict__ mem_keys, const float* __restrict__ mem_vals,
    const float* __restrict__ mem_tags, const float* __restrict__ bg,
    const float* __restrict__ qs, const float* __restrict__ wks,
    const float* __restrict__ vsl, const float* __restrict__ gsl,
    float* __restrict__ read_o,
    float* __restrict__ keys_o, float* __restrict__ vals_o, float* __restrict__ tags_o)
{
    __shared__ float R_s[4 * 528];           // h*528 + k*16 + n
    __shared__ float P_s[TV][KK + 1];
    __shared__ float q_s[4][KK], wk_s[4][KK], qt_s[4][TV], wt_s[4][TV];
    __shared__ float kg_s[4][8][KK], tg_s[4][8][TV], vg_s[4][8][DM];
    __shared__ float sc_s[4][8], mt_s[4][8];
    __shared__ float w_s[4][HH];
    __shared__ int   idx_s[4][HH], slot_s[4][HH];

    const int t    = threadIdx.x;
    const int wid  = t >> 6;
    const int lane = t & 63;

    for (int e = t; e < 2048; e += 256) R_s[(e >> 9) * 528 + (e & 511)] = R[e];
    for (int e = t; e < TV * KK; e += 256) P_s[e >> 5][e & 31] = P[e];
    const float bgv = bg[0];
    __syncthreads();

    for (int ti = 0; ti < 4; ti++) {
        const int tok = blockIdx.x * 16 + wid * 4 + ti;
        // phase 1: load q/wk (reduce K-slices)
        if (lane < 32) {
            float s = 0.f;
#pragma unroll
            for (int sl = 0; sl < PKS; sl++) s += qs[(size_t)sl * MTOK * KK + (size_t)tok * KK + lane];
            q_s[wid][lane] = s;
        } else {
            int l2 = lane - 32;
            float s = 0.f;
#pragma unroll
            for (int sl = 0; sl < PKS; sl++) s += wks[(size_t)sl * MTOK * KK + (size_t)tok * KK + l2];
            wk_s[wid][l2] = s;
        }
        WAVE_FENCE();
        // phase 2: bits -> bucket idx (lane = h*16 + n)
        {
            int h = lane >> 4, n = lane & 15;
            float s = 0.f;
#pragma unroll
            for (int k = 0; k < KK; k++) s = fmaf(q_s[wid][k], R_s[h * 528 + k * 16 + n], s);
            unsigned long long m = __ballot(s > 0.f);
            if (n == 0) idx_s[wid][h] = (int)((m >> (h * 16)) & 0xFFFFull);
        }
        // phase 3: qt (lanes 0..31), wt (lanes 32..63)
        if (lane < 32) {
            float s = 0.f;
#pragma unroll
            for (int k = 0; k < KK; k++) s = fmaf(q_s[wid][k], P_s[lane][k], s);
            qt_s[wid][lane] = tanhf(s);
        } else {
            int t2 = lane - 32;
            float s = 0.f;
#pragma unroll
            for (int k = 0; k < KK; k++) s = fmaf(wk_s[wid][k], P_s[t2][k], s);
            wt_s[wid][t2] = tanhf(s);
        }
        WAVE_FENCE();
        // phase 4: gather 8 slots
        {
            int p = lane >> 3, j = lane & 7;
            int h = p >> 1, a = p & 1;
            size_t sb = (size_t)idx_s[wid][h] * AA + a;
            *(float4*)&kg_s[wid][p][j * 4] = *(const float4*)(mem_keys + sb * KK + j * 4);
            *(float4*)&tg_s[wid][p][j * 4] = *(const float4*)(mem_tags + sb * TV + j * 4);
            *(float4*)&vg_s[wid][p][j * 8]     = *(const float4*)(mem_vals + sb * DM + j * 8);
            *(float4*)&vg_s[wid][p][j * 8 + 4] = *(const float4*)(mem_vals + sb * DM + j * 8 + 4);
        }
        WAVE_FENCE();
        // phase 5: scores (lanes 0..7) and match (lanes 8..15)
        if (lane < 8) {
            int p = lane;
            float s1 = 0.f, s2 = 0.f;
#pragma unroll
            for (int k = 0; k < KK; k++) s1 = fmaf(q_s[wid][k], kg_s[wid][p][k], s1);
#pragma unroll
            for (int k = 0; k < TV; k++) s2 = fmaf(qt_s[wid][k], tg_s[wid][p][k], s2);
            sc_s[wid][p] = s1 * 0.17677669529663688f + s2 * (1.0f / 32.0f);
        } else if (lane < 16) {
            int p = lane - 8;
            float s2 = 0.f;
#pragma unroll
            for (int k = 0; k < TV; k++) s2 = fmaf(wt_s[wid][k], tg_s[wid][p][k], s2);
            mt_s[wid][p] = s2 * (1.0f / 32.0f);
        }
        WAVE_FENCE();
        // phase 6: softmax over 8 + read (lane = d)
        {
            float sc[8];
#pragma unroll
            for (int p = 0; p < 8; p++) sc[p] = sc_s[wid][p];
            float mx = sc[0];
#pragma unroll
            for (int p = 1; p < 8; p++) mx = fmaxf(mx, sc[p]);
            float e[8], den = 0.f;
#pragma unroll
            for (int p = 0; p < 8; p++) { e[p] = expf(sc[p] - mx); den += e[p]; }
            float inv = 1.f / den;
            float r = 0.f;
#pragma unroll
            for (int p = 0; p < 8; p++) r = fmaf(e[p] * inv, vg_s[wid][p][lane], r);
            read_o[(size_t)tok * DM + lane] = r;
        }
        // phase 7: write gate (lanes 0..3 = h)
        if (lane < HH) {
            int h = lane;
            float m0v = mt_s[wid][h * 2], m1v = mt_s[wid][h * 2 + 1];
            int sl = (m1v > m0v) ? 1 : 0;
            float mm = fmaxf(m0v, m1v);
            float nov = 1.f / (1.f + expf(mm));
            float gd = bgv;
#pragma unroll
            for (int s2 = 0; s2 < PKS; s2++) gd += gsl[(size_t)s2 * MTOK + tok];
            float gg = 1.f / (1.f + expf(-gd));
            float wv = (gg > 0.5f) ? (0.1f * gg * nov) : 0.f;
            slot_s[wid][h] = sl;
            w_s[wid][h] = wv;
        }
        WAVE_FENCE();
        // phase 8: fused scatter (skip whole token if gate closed: w[0]==0 <=> all==0)
        if (w_s[wid][0] != 0.f) {
            // v reduce: lane holds v[lane]
            float vsum = 0.f;
#pragma unroll
            for (int sl = 0; sl < PKS; sl++) vsum += vsl[(size_t)sl * MTOK * DM + (size_t)tok * DM + lane];
            int h = lane >> 4, c = lane & 15;
            float wv = w_s[wid][h];
            int sl8 = slot_s[wid][h];
            size_t flat = (size_t)idx_s[wid][h] * AA + sl8;
            int p = h * 2 + sl8;
#pragma unroll
            for (int m = 0; m < 2; m++) {
                int cc = c + 16 * m;
                atomicAdd(keys_o + flat * KK + cc, wv * (wk_s[wid][cc] - kg_s[wid][p][cc]));
                atomicAdd(tags_o + flat * TV + cc, wv * (wt_s[wid][cc] - tg_s[wid][p][cc]));
            }
#pragma unroll
            for (int m = 0; m < 4; m++) {
                int cc = c + 16 * m;
                float vv = __shfl(vsum, cc);
                atomicAdd(vals_o + flat * DM + cc, wv * (vv - vg_s[wid][p][cc]));
            }
        }
        WAVE_FENCE();   // WAR: next iter overwrites wave-private buffers
    }
}

// ---------------- Kernel C: y = read @ Wout^T, 128x128 tile, 8x8/thread -------
__global__ __launch_bounds__(256, 2) void ygemm_kernel(
    const float* __restrict__ read_i, const float* __restrict__ Wout,
    float* __restrict__ y_o)
{
    __shared__ float rd_t[128][36];
    __shared__ float wo_t[128][36];
    const int t  = threadIdx.x;
    const int m0 = blockIdx.x * 128;
    const int n0 = blockIdx.y * 128;
    const int r0 = t >> 3;
    const int c8 = t & 7;
    const int ty = t >> 4;
    const int tx = t & 15;

    float acc[8][8];
#pragma unroll
    for (int i = 0; i < 8; i++)
#pragma unroll
        for (int j = 0; j < 8; j++) acc[i][j] = 0.f;

    for (int k0 = 0; k0 < DM; k0 += 32) {
        __syncthreads();
#pragma unroll
        for (int p = 0; p < 4; p++) {
            int r = r0 + 32 * p;
            *(float4*)&rd_t[r][c8 * 4] = *(const float4*)(read_i + (size_t)(m0 + r) * DM + k0 + c8 * 4);
            *(float4*)&wo_t[r][c8 * 4] = *(const float4*)(Wout  + (size_t)(n0 + r) * DM + k0 + c8 * 4);
        }
        __syncthreads();
#pragma unroll
        for (int k4 = 0; k4 < 8; k4++) {
            float4 a4[8], b4[8];
#pragma unroll
            for (int i = 0; i < 8; i++) a4[i] = *(const float4*)&rd_t[ty + 16 * i][k4 * 4];
#pragma unroll
            for (int j = 0; j < 8; j++) b4[j] = *(const float4*)&wo_t[tx + 16 * j][k4 * 4];
#pragma unroll
            for (int i = 0; i < 8; i++)
#pragma unroll
                for (int j = 0; j < 8; j++) {
                    acc[i][j] = fmaf(a4[i].x, b4[j].x, acc[i][j]);
                    acc[i][j] = fmaf(a4[i].y, b4[j].y, acc[i][j]);
                    acc[i][j] = fmaf(a4[i].z, b4[j].z, acc[i][j]);
                    acc[i][j] = fmaf(a4[i].w, b4[j].w, acc[i][j]);
                }
        }
    }
#pragma unroll
    for (int i = 0; i < 8; i++) {
        size_t row = (size_t)(m0 + ty + 16 * i) * DD + n0;
#pragma unroll
        for (int j = 0; j < 8; j++) y_o[row + tx + 16 * j] = acc[i][j];
    }
}

extern "C" void kernel_launch(void* const* d_in, const int* in_sizes, int n_in,
                              void* d_out, int out_size, void* d_ws, size_t ws_size,
                              hipStream_t stream)
{
    (void)in_sizes; (void)n_in; (void)out_size; (void)ws_size;
    const float* u    = (const float*)d_in[0];
    const float* Wq   = (const float*)d_in[1];
    const float* Ww   = (const float*)d_in[2];
    const float* Wv   = (const float*)d_in[3];
    const float* Wout = (const float*)d_in[4];
    const float* Wg   = (const float*)d_in[5];
    const float* bg   = (const float*)d_in[6];
    const float* R    = (const float*)d_in[7];
    const float* P    = (const float*)d_in[8];
    const float* mem_keys = (const float*)d_in[9];
    const float* mem_vals = (const float*)d_in[10];
    const float* mem_tags = (const float*)d_in[11];

    float* y_o    = (float*)d_out;
    float* keys_o = y_o    + (size_t)MTOK * DD;
    float* vals_o = keys_o + (size_t)TT * AA * KK;
    float* tags_o = vals_o + (size_t)TT * AA * DM;

    // proj K-slice partials live in the (not-yet-written) y region of d_out;
    // ygemm overwrites that region LAST. 8.45M floats < 16.78M available.
    float* qs  = y_o;
    float* wks = qs  + (size_t)PKS * MTOK * KK;
    float* vsl = wks + (size_t)PKS * MTOK * KK;
    float* gsl = vsl + (size_t)PKS * MTOK * DM;

    float* read_w = (float*)d_ws;

    copy_kernel<<<2048, 256, 0, stream>>>(mem_keys, mem_vals, mem_tags, keys_o);
    proj_kernel<<<128 * PKS, 256, 0, stream>>>(u, Wq, Ww, Wv, Wg, qs, wks, vsl, gsl);
    route_kernel<<<MTOK / 16, 256, 0, stream>>>(R, P, mem_keys, mem_vals, mem_tags, bg,
                                                qs, wks, vsl, gsl, read_w,
                                                keys_o, vals_o, tags_o);
    ygemm_kernel<<<dim3(MTOK / 128, DD / 128), 256, 0, stream>>>(read_w, Wout, y_o);
}